// Round 3
// baseline (197.174 us; speedup 1.0000x reference)
//
#include <hip/hip_runtime.h>

// Problem constants (fixed by reference setup_inputs)
#define N_PRE 8192
#define N_CUR 16384
#define KNN   8

// Workspace layout (bytes):
//   [0,    64K) : c2p  u32[N_CUR]     nearest-pre index per cur point
//   [64K, 192K) : pre4 float4[N_PRE]  (-2px, -2py, -2pz, |p|^2)
//   [192K,448K) : cur4 float4[N_CUR]  ( cx,   cy,   cz,  |c|^2)
//
// Comparator trick: for a fixed query q, ordering by true sqdist equals
// ordering by (|cand|^2 - 2 cand.q)  -> 3 FMA per candidate.
// d can be NEGATIVE -> monotone float->u32 key map for all comparisons.
//
// R3 structure (theory: candidate arrays are L2-resident; LDS staging +
// barriers was pure overhead, and the pop path must leave the LDS pipe):
//  * NO LDS, NO barriers in either big kernel. Candidates streamed with
//    coalesced global_load_dwordx4 (lane i reads cand s+lane), prefetch
//    depth 2 (software pipeline).
//  * Pop events ride the ballot: mask is wave-uniform -> s_ff1 ->
//    readlane -> SGPR key compare on the (idle) scalar pipe.
//      A (top-1): best (key, idx, threshold) entirely in SGPRs.
//      B (top-8): list distributed on lanes 0..7; shift-up via DPP
//        row_shr:1 (VALU, no LDS); threshold via readlane(slot 7).
//  * Fast path per candidate-pair: 3 FMA + 1 v_cmp. A: 8 cur/wave.
//    B: 4 pre/wave. 2048 waves each, no inter-wave coupling.

#define MAPPED_INF 0xFF800000u  // monotone key of +inf (empty-slot sentinel)

__device__ __forceinline__ unsigned key_of_bits(unsigned b) {
    return b ^ (0x80000000u | (unsigned)((int)b >> 31));
}
__device__ __forceinline__ float float_of_key(unsigned k) {
    unsigned b = k ^ (0x80000000u | ~(unsigned)((int)k >> 31));
    return __uint_as_float(b);
}

// ---------- prep: pack comparator-form coords ----------
__global__ __launch_bounds__(256) void prep_kernel(
        const float* __restrict__ pre, const float* __restrict__ cur,
        float4* __restrict__ pre4, float4* __restrict__ cur4) {
    int i = blockIdx.x * 256 + threadIdx.x;
    if (i < N_CUR) {
        float x = cur[i], y = cur[N_CUR + i], z = cur[2 * N_CUR + i];
        cur4[i] = make_float4(x, y, z, fmaf(x, x, fmaf(y, y, z * z)));
    }
    if (i < N_PRE) {
        float x = pre[i], y = pre[N_PRE + i], z = pre[2 * N_PRE + i];
        pre4[i] = make_float4(-2.f * x, -2.f * y, -2.f * z,
                              fmaf(x, x, fmaf(y, y, z * z)));
    }
}

// ---------- Kernel A: cur2pre argmin (L2 stream, scalar pop) ----------
// Wave owns 8 cur queries (uniform -> SGPRs). Lanes stream pre candidates.
// Running best per query is wave-shared SGPR state; events ~H(8192)=9.7
// per query. Strict < + ascending scan order => lowest index on ties.
#define Q_A 8

__device__ __forceinline__ void pop_min(float d, float& bf, unsigned& bk,
                                        unsigned& bi, int sbase) {
    unsigned long long m = __ballot(d < bf);
    while (m) {
        int src = __ffsll(m) - 1;
        unsigned fdb = (unsigned)__builtin_amdgcn_readlane(__float_as_int(d), src);
        unsigned kd = key_of_bits(fdb);
        if (kd < bk) {                 // uniform: SALU cselects
            bk = kd;
            bi = (unsigned)(sbase + src);
            bf = __uint_as_float(fdb);
        }
        m &= m - 1;
    }
}

__global__ __launch_bounds__(256) void cur2pre_kernel(
        const float4* __restrict__ pre4, const float4* __restrict__ cur4,
        unsigned* __restrict__ c2p) {
    const int lane = threadIdx.x & 63;
    const int wv   = (blockIdx.x * 256 + threadIdx.x) >> 6;  // global wave
    const int j0   = wv * Q_A;

    const float4 c0 = cur4[j0 + 0];
    const float4 c1 = cur4[j0 + 1];
    const float4 c2 = cur4[j0 + 2];
    const float4 c3 = cur4[j0 + 3];
    const float4 c4 = cur4[j0 + 4];
    const float4 c5 = cur4[j0 + 5];
    const float4 c6 = cur4[j0 + 6];
    const float4 c7 = cur4[j0 + 7];

    const float INF = __int_as_float(0x7F800000);
    float    bf0 = INF, bf1 = INF, bf2 = INF, bf3 = INF,
             bf4 = INF, bf5 = INF, bf6 = INF, bf7 = INF;
    unsigned bk0 = 0xFFFFFFFFu, bk1 = bk0, bk2 = bk0, bk3 = bk0,
             bk4 = bk0, bk5 = bk0, bk6 = bk0, bk7 = bk0;
    unsigned bi0 = 0, bi1 = 0, bi2 = 0, bi3 = 0,
             bi4 = 0, bi5 = 0, bi6 = 0, bi7 = 0;

#define PROC_A(qv, sb)                                                        \
    {                                                                         \
        float d0 = fmaf(qv.x, c0.x, fmaf(qv.y, c0.y, fmaf(qv.z, c0.z, qv.w))); \
        float d1 = fmaf(qv.x, c1.x, fmaf(qv.y, c1.y, fmaf(qv.z, c1.z, qv.w))); \
        float d2 = fmaf(qv.x, c2.x, fmaf(qv.y, c2.y, fmaf(qv.z, c2.z, qv.w))); \
        float d3 = fmaf(qv.x, c3.x, fmaf(qv.y, c3.y, fmaf(qv.z, c3.z, qv.w))); \
        float d4 = fmaf(qv.x, c4.x, fmaf(qv.y, c4.y, fmaf(qv.z, c4.z, qv.w))); \
        float d5 = fmaf(qv.x, c5.x, fmaf(qv.y, c5.y, fmaf(qv.z, c5.z, qv.w))); \
        float d6 = fmaf(qv.x, c6.x, fmaf(qv.y, c6.y, fmaf(qv.z, c6.z, qv.w))); \
        float d7 = fmaf(qv.x, c7.x, fmaf(qv.y, c7.y, fmaf(qv.z, c7.z, qv.w))); \
        pop_min(d0, bf0, bk0, bi0, sb);                                       \
        pop_min(d1, bf1, bk1, bi1, sb);                                       \
        pop_min(d2, bf2, bk2, bi2, sb);                                       \
        pop_min(d3, bf3, bk3, bi3, sb);                                       \
        pop_min(d4, bf4, bk4, bi4, sb);                                       \
        pop_min(d5, bf5, bk5, bi5, sb);                                       \
        pop_min(d6, bf6, bk6, bi6, sb);                                       \
        pop_min(d7, bf7, bk7, bi7, sb);                                       \
    }

    float4 qa = pre4[lane];
    float4 qb = pre4[64 + lane];
    for (int s = 0; s < N_PRE; s += 128) {
        float4 qn0 = pre4[((s + 128) & (N_PRE - 1)) + lane];
        float4 qn1 = pre4[((s + 192) & (N_PRE - 1)) + lane];
        PROC_A(qa, s);
        PROC_A(qb, s + 64);
        qa = qn0;
        qb = qn1;
    }
#undef PROC_A

    // scatter the 8 uniform results: lane q writes query q's best index
    unsigned ov = bi0;
    ov = (lane == 1) ? bi1 : ov;
    ov = (lane == 2) ? bi2 : ov;
    ov = (lane == 3) ? bi3 : ov;
    ov = (lane == 4) ? bi4 : ov;
    ov = (lane == 5) ? bi5 : ov;
    ov = (lane == 6) ? bi6 : ov;
    ov = (lane == 7) ? bi7 : ov;
    if (lane < 8) c2p[j0 + lane] = ov;
}

// ---------- Kernel B: per-pre top-8 + masked mean (L2 stream, DPP insert) --
// Wave owns 4 pre queries (uniform -> SGPRs). Lanes stream cur candidates.
// Top-8 (ascending key) distributed: lane t in 0..7 holds slot t.
// Insert: shift-up via DPP row_shr:1, uniform key from readlane, 2 v_cmp +
// 4 cndmask; threshold = readlane(slot 7). ~9 VALU / event, no LDS ops.
#define P_B 4

__device__ __forceinline__ void pop_top8(float d, float& t8, unsigned& ld,
                                         unsigned& li, int sbase) {
    unsigned long long m = __ballot(d < t8);
    while (m) {
        int src = __ffsll(m) - 1;
        unsigned fdb = (unsigned)__builtin_amdgcn_readlane(__float_as_int(d), src);
        unsigned kd = key_of_bits(fdb);            // uniform
        unsigned kj = (unsigned)(sbase + src);     // uniform
        // shift-up within 16-lane row; lane 0 receives old=0
        unsigned ud = (unsigned)__builtin_amdgcn_update_dpp(
            0, (int)ld, 0x111, 0xF, 0xF, false);
        unsigned uj = (unsigned)__builtin_amdgcn_update_dpp(
            0, (int)li, 0x111, 0xF, 0xF, false);
        bool hi = kd < ud;   // belongs below slot-1 -> take shifted value
        bool lo = kd < ld;   // belongs here -> take new
        ld = hi ? ud : (lo ? kd : ld);
        li = hi ? uj : (lo ? kj : li);
        unsigned k7 = (unsigned)__builtin_amdgcn_readlane((int)ld, 7);
        t8 = float_of_key(k7);
        m = (m & (m - 1)) & __ballot(d < t8);
    }
}

__global__ __launch_bounds__(256) void knn_finalize_kernel(
        const float4* __restrict__ pre4, const float4* __restrict__ cur4,
        const float* __restrict__ ups,
        const unsigned* __restrict__ c2p,
        float* __restrict__ out) {
    const int lane = threadIdx.x & 63;
    const int wv   = (blockIdx.x * 256 + threadIdx.x) >> 6;  // global wave
    const int i0   = wv * P_B;

    const float4 p0 = pre4[i0 + 0];   // (-2p, |p|^2), wave-uniform
    const float4 p1 = pre4[i0 + 1];
    const float4 p2 = pre4[i0 + 2];
    const float4 p3 = pre4[i0 + 3];

    const float INF = __int_as_float(0x7F800000);
    unsigned ld0 = MAPPED_INF, li0 = 0, ld1 = MAPPED_INF, li1 = 0;
    unsigned ld2 = MAPPED_INF, li2 = 0, ld3 = MAPPED_INF, li3 = 0;
    float t0 = INF, t1 = INF, t2 = INF, t3 = INF;

#define PROC_B(cv, sb)                                                        \
    {                                                                         \
        float d0 = fmaf(p0.x, cv.x, fmaf(p0.y, cv.y, fmaf(p0.z, cv.z, cv.w))); \
        float d1 = fmaf(p1.x, cv.x, fmaf(p1.y, cv.y, fmaf(p1.z, cv.z, cv.w))); \
        float d2 = fmaf(p2.x, cv.x, fmaf(p2.y, cv.y, fmaf(p2.z, cv.z, cv.w))); \
        float d3 = fmaf(p3.x, cv.x, fmaf(p3.y, cv.y, fmaf(p3.z, cv.z, cv.w))); \
        pop_top8(d0, t0, ld0, li0, sb);                                       \
        pop_top8(d1, t1, ld1, li1, sb);                                       \
        pop_top8(d2, t2, ld2, li2, sb);                                       \
        pop_top8(d3, t3, ld3, li3, sb);                                       \
    }

    float4 ca = cur4[lane];
    float4 cb = cur4[64 + lane];
    for (int s = 0; s < N_CUR; s += 128) {
        float4 cn0 = cur4[((s + 128) & (N_CUR - 1)) + lane];
        float4 cn1 = cur4[((s + 192) & (N_CUR - 1)) + lane];
        PROC_B(ca, s);
        PROC_B(cb, s + 64);
        ca = cn0;
        cb = cn1;
    }
#undef PROC_B

    // finalize each list: lanes 0..7 hold slots 0..7 (ascending).
    // True distance recomputed in direct form; p recovered exactly (* -0.5).
#define FIN_B(pp, lip, off)                                                   \
    {                                                                         \
        float acc = 0.f;                                                      \
        if (lane < 8) {                                                       \
            unsigned j = lip;                                                 \
            float4 cc = cur4[j];                                              \
            float px = -0.5f * pp.x, py = -0.5f * pp.y, pz = -0.5f * pp.z;    \
            float dx = cc.x - px, dy = cc.y - py, dz = cc.z - pz;             \
            float dsq = fmaf(dx, dx, fmaf(dy, dy, dz * dz));                  \
            acc = (c2p[j] == (unsigned)(i0 + off)) ? sqrtf(dsq) : 0.f;        \
        }                                                                     \
        acc += __shfl_xor(acc, 1);                                            \
        acc += __shfl_xor(acc, 2);                                            \
        acc += __shfl_xor(acc, 4);                                            \
        if (lane == 0) out[i0 + off] = acc / ups[i0 + off];                   \
    }

    FIN_B(p0, li0, 0)
    FIN_B(p1, li1, 1)
    FIN_B(p2, li2, 2)
    FIN_B(p3, li3, 3)
#undef FIN_B
}

// ---------- launch ----------
extern "C" void kernel_launch(void* const* d_in, const int* in_sizes, int n_in,
                              void* d_out, int out_size, void* d_ws, size_t ws_size,
                              hipStream_t stream) {
    const float* pre = (const float*)d_in[0];   // (1,3,8192)
    const float* cur = (const float*)d_in[1];   // (1,3,16384)
    const float* ups = (const float*)d_in[2];   // (1,8192)
    float* out = (float*)d_out;                 // (1,8192)

    char* ws = (char*)d_ws;
    unsigned* c2p = (unsigned*)ws;                    //  64 KB
    float4*   pre4 = (float4*)(ws + 65536);           // 128 KB
    float4*   cur4 = (float4*)(ws + 65536 + 131072);  // 256 KB

    prep_kernel<<<N_CUR / 256, 256, 0, stream>>>(pre, cur, pre4, cur4);

    // A: 16384 cur / (8 per wave * 4 waves per block) = 512 blocks
    cur2pre_kernel<<<N_CUR / (Q_A * 4), 256, 0, stream>>>(pre4, cur4, c2p);

    // B: 8192 pre / (4 per wave * 4 waves per block) = 512 blocks
    knn_finalize_kernel<<<N_PRE / (P_B * 4), 256, 0, stream>>>(pre4, cur4, ups, c2p, out);
}

// Round 4
// 155.385 us; speedup vs baseline: 1.2689x; 1.2689x over previous
//
#include <hip/hip_runtime.h>

// Problem constants (fixed by reference setup_inputs)
#define N_PRE 8192
#define N_CUR 16384
#define KNN   8

// Workspace layout (bytes):
//   [0,    64K) : c2p  u32[N_CUR]     nearest-pre index per cur point
//   [64K, 192K) : pre4 float4[N_PRE]  (-2px, -2py, -2pz, |p|^2)
//   [192K,448K) : cur4 float4[N_CUR]  ( cx,   cy,   cz,  |c|^2)
//
// Comparator trick: for a fixed query q, ordering by true sqdist equals
// ordering by (|cand|^2 - 2 cand.q)  -> 3 FMA per candidate.
// d can be NEGATIVE -> monotone float->u32 key map for all key compares.
//
// R4 (post-mortem-driven recombination of measured-best pieces):
//  A: lane=candidate stream (global prefetch depth-2, no LDS/barriers),
//     Q=8 queries/wave in registers, per-lane BRANCHLESS running min —
//     NO ballots/events (R3's pop_min storm was the regression: first
//     chunk = 64 serial pops/query). Final merge: packed (key<<32|idx)
//     u64 butterfly (tie-break proven R0-R2).
//  B: R1's proven LDS-tile ballot-pop structure (best measured 65.3us,
//     LDS-pipe-bound: 41us ds_read + ~23us shfl events), fixed two ways:
//     P=2 pre/wave halves the ds_read re-reads; insert path uses DPP
//     row_shr:1 + readlane (R3-verified) so events leave the LDS pipe.

#define MAPPED_INF 0xFF800000u  // monotone key of +inf (empty-slot sentinel)

__device__ __forceinline__ unsigned key_of_bits(unsigned b) {
    return b ^ (0x80000000u | (unsigned)((int)b >> 31));
}
__device__ __forceinline__ float float_of_key(unsigned k) {
    unsigned b = k ^ (0x80000000u | ~(unsigned)((int)k >> 31));
    return __uint_as_float(b);
}

// ---------- prep: pack comparator-form coords ----------
__global__ __launch_bounds__(256) void prep_kernel(
        const float* __restrict__ pre, const float* __restrict__ cur,
        float4* __restrict__ pre4, float4* __restrict__ cur4) {
    int i = blockIdx.x * 256 + threadIdx.x;
    if (i < N_CUR) {
        float x = cur[i], y = cur[N_CUR + i], z = cur[2 * N_CUR + i];
        cur4[i] = make_float4(x, y, z, fmaf(x, x, fmaf(y, y, z * z)));
    }
    if (i < N_PRE) {
        float x = pre[i], y = pre[N_PRE + i], z = pre[2 * N_PRE + i];
        pre4[i] = make_float4(-2.f * x, -2.f * y, -2.f * z,
                              fmaf(x, x, fmaf(y, y, z * z)));
    }
}

// ---------- Kernel A: cur2pre argmin ----------
// Wave owns Q_A=8 cur queries (registers). Lanes stream pre candidates
// from global (L2-resident, prefetch depth 2). Per candidate chunk of 64:
// 8 x (3 FMA + 1 cmp + 2 cndmask) + 1 idx add — pure VALU, no events.
// Per-lane stream is ascending-index with strict <  -> lowest idx on
// ties within lane; cross-lane: packed (key<<32|idx) u64 butterfly min.
#define Q_A 8

__global__ __launch_bounds__(256) void cur2pre_kernel(
        const float4* __restrict__ pre4, const float4* __restrict__ cur4,
        unsigned* __restrict__ c2p) {
    const int lane = threadIdx.x & 63;
    const int wv   = (blockIdx.x * 256 + threadIdx.x) >> 6;  // global wave
    const int j0   = wv * Q_A;

    const float4 c0 = cur4[j0 + 0];
    const float4 c1 = cur4[j0 + 1];
    const float4 c2 = cur4[j0 + 2];
    const float4 c3 = cur4[j0 + 3];
    const float4 c4 = cur4[j0 + 4];
    const float4 c5 = cur4[j0 + 5];
    const float4 c6 = cur4[j0 + 6];
    const float4 c7 = cur4[j0 + 7];

    const float INF = __int_as_float(0x7F800000);
    float b0 = INF, b1 = INF, b2 = INF, b3 = INF,
          b4 = INF, b5 = INF, b6 = INF, b7 = INF;
    int   i0 = 0, i1 = 0, i2 = 0, i3 = 0, i4 = 0, i5 = 0, i6 = 0, i7 = 0;

#define STEP_A(qv, sb)                                                         \
    {                                                                          \
        int idxv = (sb) + lane;                                                \
        float d; bool c;                                                       \
        d = fmaf(qv.x, c0.x, fmaf(qv.y, c0.y, fmaf(qv.z, c0.z, qv.w)));        \
        c = d < b0; b0 = c ? d : b0; i0 = c ? idxv : i0;                       \
        d = fmaf(qv.x, c1.x, fmaf(qv.y, c1.y, fmaf(qv.z, c1.z, qv.w)));        \
        c = d < b1; b1 = c ? d : b1; i1 = c ? idxv : i1;                       \
        d = fmaf(qv.x, c2.x, fmaf(qv.y, c2.y, fmaf(qv.z, c2.z, qv.w)));        \
        c = d < b2; b2 = c ? d : b2; i2 = c ? idxv : i2;                       \
        d = fmaf(qv.x, c3.x, fmaf(qv.y, c3.y, fmaf(qv.z, c3.z, qv.w)));        \
        c = d < b3; b3 = c ? d : b3; i3 = c ? idxv : i3;                       \
        d = fmaf(qv.x, c4.x, fmaf(qv.y, c4.y, fmaf(qv.z, c4.z, qv.w)));        \
        c = d < b4; b4 = c ? d : b4; i4 = c ? idxv : i4;                       \
        d = fmaf(qv.x, c5.x, fmaf(qv.y, c5.y, fmaf(qv.z, c5.z, qv.w)));        \
        c = d < b5; b5 = c ? d : b5; i5 = c ? idxv : i5;                       \
        d = fmaf(qv.x, c6.x, fmaf(qv.y, c6.y, fmaf(qv.z, c6.z, qv.w)));        \
        c = d < b6; b6 = c ? d : b6; i6 = c ? idxv : i6;                       \
        d = fmaf(qv.x, c7.x, fmaf(qv.y, c7.y, fmaf(qv.z, c7.z, qv.w)));        \
        c = d < b7; b7 = c ? d : b7; i7 = c ? idxv : i7;                       \
    }

    float4 qa = pre4[lane];
    float4 qb = pre4[64 + lane];
    for (int s = 0; s < N_PRE; s += 128) {
        float4 qn0 = pre4[((s + 128) & (N_PRE - 1)) + lane];
        float4 qn1 = pre4[((s + 192) & (N_PRE - 1)) + lane];
        STEP_A(qa, s);
        STEP_A(qb, s + 64);
        qa = qn0;
        qb = qn1;
    }
#undef STEP_A

    // packed (key,idx) butterfly min: lowest key, then lowest idx
    unsigned long long v0 = (((unsigned long long)key_of_bits(__float_as_uint(b0))) << 32) | (unsigned)i0;
    unsigned long long v1 = (((unsigned long long)key_of_bits(__float_as_uint(b1))) << 32) | (unsigned)i1;
    unsigned long long v2 = (((unsigned long long)key_of_bits(__float_as_uint(b2))) << 32) | (unsigned)i2;
    unsigned long long v3 = (((unsigned long long)key_of_bits(__float_as_uint(b3))) << 32) | (unsigned)i3;
    unsigned long long v4 = (((unsigned long long)key_of_bits(__float_as_uint(b4))) << 32) | (unsigned)i4;
    unsigned long long v5 = (((unsigned long long)key_of_bits(__float_as_uint(b5))) << 32) | (unsigned)i5;
    unsigned long long v6 = (((unsigned long long)key_of_bits(__float_as_uint(b6))) << 32) | (unsigned)i6;
    unsigned long long v7 = (((unsigned long long)key_of_bits(__float_as_uint(b7))) << 32) | (unsigned)i7;
#pragma unroll
    for (int off = 32; off > 0; off >>= 1) {
        unsigned long long o;
        o = __shfl_xor(v0, off); v0 = (o < v0) ? o : v0;
        o = __shfl_xor(v1, off); v1 = (o < v1) ? o : v1;
        o = __shfl_xor(v2, off); v2 = (o < v2) ? o : v2;
        o = __shfl_xor(v3, off); v3 = (o < v3) ? o : v3;
        o = __shfl_xor(v4, off); v4 = (o < v4) ? o : v4;
        o = __shfl_xor(v5, off); v5 = (o < v5) ? o : v5;
        o = __shfl_xor(v6, off); v6 = (o < v6) ? o : v6;
    }
    {
        // v7 folded into the same loop shape (kept separate to stay under
        // macro width); do its butterfly here.
#pragma unroll
        for (int off = 32; off > 0; off >>= 1) {
            unsigned long long o = __shfl_xor(v7, off);
            v7 = (o < v7) ? o : v7;
        }
    }

    unsigned r = (unsigned)v0;
    r = (lane == 1) ? (unsigned)v1 : r;
    r = (lane == 2) ? (unsigned)v2 : r;
    r = (lane == 3) ? (unsigned)v3 : r;
    r = (lane == 4) ? (unsigned)v4 : r;
    r = (lane == 5) ? (unsigned)v5 : r;
    r = (lane == 6) ? (unsigned)v6 : r;
    r = (lane == 7) ? (unsigned)v7 : r;
    if (lane < 8) c2p[j0 + lane] = r;
}

// ---------- Kernel B: per-pre top-8 + masked mean ----------
// R1 structure (proven): LDS cur tile, ballot-gated pop events, list
// distributed on lanes 0..7 ascending. Changes: P=2 pre/wave (halves
// ds_read re-reads), insert via DPP row_shr:1 + readlane (R3-verified,
// no LDS-pipe ops in the event path). Block 512, grid 512 -> 2 blocks/CU.
#define TILE_B 2048

__device__ __forceinline__ void pop_top8(float d, float& t8, unsigned& ld,
                                         unsigned& li, int jbase) {
    unsigned long long m = __ballot(d < t8);
    while (m) {
        int src = __ffsll(m) - 1;
        unsigned fdb = (unsigned)__builtin_amdgcn_readlane(__float_as_int(d), src);
        unsigned kd = key_of_bits(fdb);            // uniform (SALU)
        unsigned kj = (unsigned)(jbase + src);     // uniform (SALU)
        // shift-up within 16-lane row; lane 0 receives old=0
        unsigned ud = (unsigned)__builtin_amdgcn_update_dpp(
            0, (int)ld, 0x111, 0xF, 0xF, false);
        unsigned uj = (unsigned)__builtin_amdgcn_update_dpp(
            0, (int)li, 0x111, 0xF, 0xF, false);
        bool hi = kd < ud;   // belongs below slot-1 -> take shifted value
        bool lo = kd < ld;   // belongs here -> take new
        ld = hi ? ud : (lo ? kd : ld);
        li = hi ? uj : (lo ? kj : li);
        unsigned k7 = (unsigned)__builtin_amdgcn_readlane((int)ld, 7);
        t8 = float_of_key(k7);
        m = (m & (m - 1)) & __ballot(d < t8);
    }
}

__global__ __launch_bounds__(512) void knn_finalize_kernel(
        const float4* __restrict__ pre4, const float4* __restrict__ cur4,
        const float* __restrict__ ups,
        const unsigned* __restrict__ c2p,
        float* __restrict__ out) {
    __shared__ float4 sc[TILE_B];
    const int tid  = threadIdx.x;
    const int lane = tid & 63;
    const int w    = tid >> 6;
    const int ia   = blockIdx.x * 16 + w * 2;   // 8 waves x 2 pre each
    const int ib   = ia + 1;

    const float4 p0 = pre4[ia];   // (-2p, |p|^2), wave-uniform
    const float4 p1 = pre4[ib];

    const float INF = __int_as_float(0x7F800000);
    unsigned ld0 = MAPPED_INF, li0 = 0, ld1 = MAPPED_INF, li1 = 0;
    float t80 = INF, t81 = INF;

    for (int tile = 0; tile < N_CUR; tile += TILE_B) {
        __syncthreads();
        for (int k = tid; k < TILE_B; k += 512) sc[k] = cur4[tile + k];
        __syncthreads();

#pragma unroll 4
        for (int s = 0; s < TILE_B; s += 64) {
            float4 c = sc[s + lane];
            float d0 = fmaf(p0.x, c.x, fmaf(p0.y, c.y, fmaf(p0.z, c.z, c.w)));
            float d1 = fmaf(p1.x, c.x, fmaf(p1.y, c.y, fmaf(p1.z, c.z, c.w)));
            const int jbase = tile + s;
            pop_top8(d0, t80, ld0, li0, jbase);
            pop_top8(d1, t81, ld1, li1, jbase);
        }
    }

    // finalize: lanes 0..7 hold slots 0..7 (ascending) of each list.
    // True distance recomputed in direct form; p recovered exactly (* -0.5).
    {
        float acc = 0.f;
        if (lane < 8) {
            unsigned j = li0;
            float4 cc = cur4[j];
            float px = -0.5f * p0.x, py = -0.5f * p0.y, pz = -0.5f * p0.z;
            float dx = cc.x - px, dy = cc.y - py, dz = cc.z - pz;
            float dsq = fmaf(dx, dx, fmaf(dy, dy, dz * dz));
            acc = (c2p[j] == (unsigned)ia) ? sqrtf(dsq) : 0.f;
        }
        acc += __shfl_xor(acc, 1);
        acc += __shfl_xor(acc, 2);
        acc += __shfl_xor(acc, 4);
        if (lane == 0) out[ia] = acc / ups[ia];
    }
    {
        float acc = 0.f;
        if (lane < 8) {
            unsigned j = li1;
            float4 cc = cur4[j];
            float px = -0.5f * p1.x, py = -0.5f * p1.y, pz = -0.5f * p1.z;
            float dx = cc.x - px, dy = cc.y - py, dz = cc.z - pz;
            float dsq = fmaf(dx, dx, fmaf(dy, dy, dz * dz));
            acc = (c2p[j] == (unsigned)ib) ? sqrtf(dsq) : 0.f;
        }
        acc += __shfl_xor(acc, 1);
        acc += __shfl_xor(acc, 2);
        acc += __shfl_xor(acc, 4);
        if (lane == 0) out[ib] = acc / ups[ib];
    }
}

// ---------- launch ----------
extern "C" void kernel_launch(void* const* d_in, const int* in_sizes, int n_in,
                              void* d_out, int out_size, void* d_ws, size_t ws_size,
                              hipStream_t stream) {
    const float* pre = (const float*)d_in[0];   // (1,3,8192)
    const float* cur = (const float*)d_in[1];   // (1,3,16384)
    const float* ups = (const float*)d_in[2];   // (1,8192)
    float* out = (float*)d_out;                 // (1,8192)

    char* ws = (char*)d_ws;
    unsigned* c2p = (unsigned*)ws;                    //  64 KB
    float4*   pre4 = (float4*)(ws + 65536);           // 128 KB
    float4*   cur4 = (float4*)(ws + 65536 + 131072);  // 256 KB

    prep_kernel<<<N_CUR / 256, 256, 0, stream>>>(pre, cur, pre4, cur4);

    // A: 16384 cur / (8 per wave * 4 waves per block) = 512 blocks
    cur2pre_kernel<<<N_CUR / (Q_A * 4), 256, 0, stream>>>(pre4, cur4, c2p);

    // B: 8192 pre / (2 per wave * 8 waves per block) = 512 blocks
    knn_finalize_kernel<<<N_PRE / 16, 512, 0, stream>>>(pre4, cur4, ups, c2p, out);
}